// Round 4
// baseline (3080.333 us; speedup 1.0000x reference)
//
#include <hip/hip_runtime.h>
#include <math.h>

#define N_NODES 100000
#define E_EDGES 1600000
#define S_SNAP  4
#define D_IN    128
#define H_DIM   256
#define P_POST  10000

// ---------- bf16 helpers (used ONLY for the h workspace buffer) ----------
__device__ __forceinline__ float bf2f(unsigned short u) {
    union { unsigned int i; float f; } v; v.i = ((unsigned int)u) << 16; return v.f;
}
__device__ __forceinline__ unsigned short f2bf(float f) {
    union { float f; unsigned int i; } v; v.f = f;
    unsigned int lsb = (v.i >> 16) & 1u;
    v.i += 0x7fffu + lsb;                 // round-nearest-even
    return (unsigned short)(v.i >> 16);
}

// ---------------- utility ----------------
__global__ void zero32_kernel(unsigned int* __restrict__ p, int n) {
    int i = blockIdx.x * blockDim.x + threadIdx.x;
    if (i < n) p[i] = 0u;
}

// ---------------- graph prep ----------------
__global__ void hist_kernel(const int* __restrict__ dst, int* __restrict__ deg) {
    int i = blockIdx.x * blockDim.x + threadIdx.x;
    if (i < E_EDGES) atomicAdd(&deg[dst[i]], 1);
}

__global__ void dinv_kernel(const int* __restrict__ deg, float* __restrict__ dinv) {
    int i = blockIdx.x * blockDim.x + threadIdx.x;
    if (i < N_NODES) dinv[i] = rsqrtf((float)(deg[i] + 1));  // +1 self-loop
}

// single-block exclusive scan of deg[N] -> rowptr[N+1], also copies to cursor
__global__ __launch_bounds__(1024) void scan_kernel(const int* __restrict__ deg,
        int* __restrict__ rowptr, int* __restrict__ cursor) {
    __shared__ int sums[1024];
    const int n = N_NODES;
    int tid = threadIdx.x;
    int chunk = (n + 1023) >> 10;
    int begin = tid * chunk;
    int end = begin + chunk; if (end > n) end = n;
    int s = 0;
    for (int i = begin; i < end; ++i) s += deg[i];
    sums[tid] = s;
    __syncthreads();
    for (int off = 1; off < 1024; off <<= 1) {
        int v = (tid >= off) ? sums[tid - off] : 0;
        __syncthreads();
        sums[tid] += v;
        __syncthreads();
    }
    int run = (tid == 0) ? 0 : sums[tid - 1];
    for (int i = begin; i < end; ++i) {
        rowptr[i] = run; cursor[i] = run;
        run += deg[i];
    }
    if (tid == 0) rowptr[n] = sums[1023];
}

__global__ void fill_kernel(const int* __restrict__ src, const int* __restrict__ dst,
        int* __restrict__ cursor, int* __restrict__ csrsrc) {
    int i = blockIdx.x * blockDim.x + threadIdx.x;
    if (i < E_EDGES) {
        int d = dst[i];
        int pos = atomicAdd(&cursor[d], 1);
        csrsrc[pos] = src[i];
    }
}

// ---------------- SpMM layer 0: t0 = Ahat @ x   (x fp32 [N,128] -> t0 fp32 [N,128]) ----
// one wave per dst row; lane holds 2 cols (float2 = 8B/lane, 512B coalesced per edge)
__global__ __launch_bounds__(256) void spmm_x_kernel(const float* __restrict__ x,
        const float* __restrict__ dinv, const int* __restrict__ rowptr,
        const int* __restrict__ csrsrc, float* __restrict__ t0) {
    int r = (blockIdx.x << 2) + (threadIdx.x >> 6);
    int lane = threadIdx.x & 63;
    int e0 = rowptr[r], e1 = rowptr[r + 1];
    float di = dinv[r];
    float ax = 0.f, ay = 0.f;
    const float2* xp = (const float2*)x;        // row stride 64 float2
    for (int e = e0; e < e1; ++e) {
        int s = csrsrc[e];
        float w = dinv[s] * di;
        float2 u = xp[(size_t)s * 64 + lane];
        ax = fmaf(u.x, w, ax);
        ay = fmaf(u.y, w, ay);
    }
    float2 u = xp[(size_t)r * 64 + lane];       // self loop, weight dinv^2
    float wd = di * di;
    ax = fmaf(u.x, wd, ax);
    ay = fmaf(u.y, wd, ay);
    ((float2*)t0)[(size_t)r * 64 + lane] = make_float2(ax, ay);
}

// ---------------- SpMM layer 1 (post rows only): t1p[p] = (Ahat @ h)[post[p]] ----------
// h bf16 [N,256]; lane holds 4 cols (ushort4 = 8B/lane, 512B coalesced per edge)
__global__ __launch_bounds__(256) void spmm_h_post_kernel(const unsigned short* __restrict__ h,
        const float* __restrict__ dinv, const int* __restrict__ rowptr,
        const int* __restrict__ csrsrc, const int* __restrict__ post,
        float* __restrict__ t1p) {
    int p = (blockIdx.x << 2) + (threadIdx.x >> 6);
    int lane = threadIdx.x & 63;
    int r = post[p];
    int e0 = rowptr[r], e1 = rowptr[r + 1];
    float di = dinv[r];
    float4 acc = make_float4(0.f, 0.f, 0.f, 0.f);
    const ushort4* hp = (const ushort4*)h;      // row stride 64 ushort4
    for (int e = e0; e < e1; ++e) {
        int s = csrsrc[e];
        float w = dinv[s] * di;
        ushort4 u = hp[(size_t)s * 64 + lane];
        acc.x = fmaf(bf2f(u.x), w, acc.x);
        acc.y = fmaf(bf2f(u.y), w, acc.y);
        acc.z = fmaf(bf2f(u.z), w, acc.z);
        acc.w = fmaf(bf2f(u.w), w, acc.w);
    }
    ushort4 u = hp[(size_t)r * 64 + lane];
    float wd = di * di;
    acc.x = fmaf(bf2f(u.x), wd, acc.x);
    acc.y = fmaf(bf2f(u.y), wd, acc.y);
    acc.z = fmaf(bf2f(u.z), wd, acc.z);
    acc.w = fmaf(bf2f(u.w), wd, acc.w);
    ((float4*)t1p)[(size_t)p * 64 + lane] = acc;
}

// ------- GEMM layer 0: h = relu(t0 @ W1 + b1)  (A fp32 [M,K], B fp32 [K,256], C bf16) ----
// 64x64 tile, 256 threads, 4x4/thread, BK=16
__global__ __launch_bounds__(256) void gemm_l0_kernel(const float* __restrict__ A,
        const float* __restrict__ B, const float* __restrict__ bias,
        unsigned short* __restrict__ C, int M, int K) {
    __shared__ float As[16][68];
    __shared__ float Bs[16][68];
    int tid = threadIdx.x;
    int tx = tid & 15, ty = tid >> 4;
    int m0 = blockIdx.x * 64, n0 = blockIdx.y * 64;
    int lar = tid >> 2;            // 0..63 A row in tile
    int lac = (tid & 3) << 2;      // 0,4,8,12 A col in tile
    int lbr = tid >> 4;            // 0..15 B row in tile
    int lbc = (tid & 15) << 2;     // 0..60 B col in tile
    float acc[4][4] = {};
    for (int kk = 0; kk < K; kk += 16) {
        float4 av = make_float4(0.f, 0.f, 0.f, 0.f);
        if (m0 + lar < M) av = *(const float4*)(A + (size_t)(m0 + lar) * K + kk + lac);
        float4 bv = *(const float4*)(B + (size_t)(kk + lbr) * 256 + n0 + lbc);
        __syncthreads();
        As[lac + 0][lar] = av.x; As[lac + 1][lar] = av.y;
        As[lac + 2][lar] = av.z; As[lac + 3][lar] = av.w;
        *(float4*)(&Bs[lbr][lbc]) = bv;
        __syncthreads();
        #pragma unroll
        for (int k = 0; k < 16; ++k) {
            float4 a4 = *(const float4*)(&As[k][ty << 2]);
            float4 b4 = *(const float4*)(&Bs[k][tx << 2]);
            float a[4] = {a4.x, a4.y, a4.z, a4.w};
            float b[4] = {b4.x, b4.y, b4.z, b4.w};
            #pragma unroll
            for (int i = 0; i < 4; ++i)
                #pragma unroll
                for (int j = 0; j < 4; ++j)
                    acc[i][j] = fmaf(a[i], b[j], acc[i][j]);
        }
    }
    int nb = n0 + (tx << 2);
    float4 bv = *(const float4*)(bias + nb);
    float bf[4] = {bv.x, bv.y, bv.z, bv.w};
    #pragma unroll
    for (int i = 0; i < 4; ++i) {
        int m = m0 + (ty << 2) + i;
        if (m < M) {
            ushort4 o;
            o.x = f2bf(fmaxf(acc[i][0] + bf[0], 0.f));
            o.y = f2bf(fmaxf(acc[i][1] + bf[1], 0.f));
            o.z = f2bf(fmaxf(acc[i][2] + bf[2], 0.f));
            o.w = f2bf(fmaxf(acc[i][3] + bf[3], 0.f));
            *(ushort4*)(C + (size_t)m * 256 + nb) = o;
        }
    }
}

// ------- GEMM layer 1 (post rows): accP += t1p @ W2 + b2 + h[post]  (accP fp32 [P,256]) ---
__global__ __launch_bounds__(256) void gemm_l1_kernel(const float* __restrict__ A,
        const float* __restrict__ B, const float* __restrict__ b2,
        const unsigned short* __restrict__ h, const int* __restrict__ post,
        float* __restrict__ accP, int M) {
    __shared__ float As[16][68];
    __shared__ float Bs[16][68];
    int tid = threadIdx.x;
    int tx = tid & 15, ty = tid >> 4;
    int m0 = blockIdx.x * 64, n0 = blockIdx.y * 64;
    int lar = tid >> 2;
    int lac = (tid & 3) << 2;
    int lbr = tid >> 4;
    int lbc = (tid & 15) << 2;
    float acc[4][4] = {};
    for (int kk = 0; kk < 256; kk += 16) {
        float4 av = make_float4(0.f, 0.f, 0.f, 0.f);
        if (m0 + lar < M) av = *(const float4*)(A + (size_t)(m0 + lar) * 256 + kk + lac);
        float4 bv = *(const float4*)(B + (size_t)(kk + lbr) * 256 + n0 + lbc);
        __syncthreads();
        As[lac + 0][lar] = av.x; As[lac + 1][lar] = av.y;
        As[lac + 2][lar] = av.z; As[lac + 3][lar] = av.w;
        *(float4*)(&Bs[lbr][lbc]) = bv;
        __syncthreads();
        #pragma unroll
        for (int k = 0; k < 16; ++k) {
            float4 a4 = *(const float4*)(&As[k][ty << 2]);
            float4 b4 = *(const float4*)(&Bs[k][tx << 2]);
            float a[4] = {a4.x, a4.y, a4.z, a4.w};
            float b[4] = {b4.x, b4.y, b4.z, b4.w};
            #pragma unroll
            for (int i = 0; i < 4; ++i)
                #pragma unroll
                for (int j = 0; j < 4; ++j)
                    acc[i][j] = fmaf(a[i], b[j], acc[i][j]);
        }
    }
    int nb = n0 + (tx << 2);
    float4 bv = *(const float4*)(b2 + nb);
    float bf[4] = {bv.x, bv.y, bv.z, bv.w};
    #pragma unroll
    for (int i = 0; i < 4; ++i) {
        int m = m0 + (ty << 2) + i;
        if (m < M) {
            int node = post[m];
            ushort4 hr = *(const ushort4*)(h + (size_t)node * 256 + nb);
            float4 a = *(float4*)(accP + (size_t)m * 256 + nb);
            a.x += acc[i][0] + bf[0] + bf2f(hr.x);
            a.y += acc[i][1] + bf[1] + bf2f(hr.y);
            a.z += acc[i][2] + bf[2] + bf2f(hr.z);
            a.w += acc[i][3] + bf[3] + bf2f(hr.w);
            *(float4*)(accP + (size_t)m * 256 + nb) = a;
        }
    }
}

// ---------------- classifier: sigmoid(relu(accP/4 @ Wc1 + bc1) @ Wc2 + bc2) ----------------
__global__ __launch_bounds__(128) void classifier_kernel(const float* __restrict__ accP,
        const float* __restrict__ Wc1, const float* __restrict__ bc1,
        const float* __restrict__ Wc2, const float* __restrict__ bc2,
        float* __restrict__ out) {
    __shared__ float arow[8][256];
    __shared__ float red[2][8];
    int p0 = blockIdx.x << 3;
    int tid = threadIdx.x;     // 128 threads; tid == hidden col
    for (int idx = tid; idx < 8 * 256; idx += 128) {
        int pl = idx >> 8, k = idx & 255;
        arow[pl][k] = 0.25f * accP[(size_t)(p0 + pl) * 256 + k];  // mean over S=4
    }
    __syncthreads();
    float s[8];
    float b = bc1[tid];
    #pragma unroll
    for (int pl = 0; pl < 8; ++pl) s[pl] = b;
    for (int k = 0; k < 256; ++k) {
        float wv = Wc1[k * 128 + tid];
        #pragma unroll
        for (int pl = 0; pl < 8; ++pl) s[pl] = fmaf(arow[pl][k], wv, s[pl]);
    }
    float wc2 = Wc2[tid];
    float part[8];
    #pragma unroll
    for (int pl = 0; pl < 8; ++pl) part[pl] = fmaxf(s[pl], 0.f) * wc2;
    #pragma unroll
    for (int off = 32; off > 0; off >>= 1)
        #pragma unroll
        for (int pl = 0; pl < 8; ++pl) part[pl] += __shfl_down(part[pl], off, 64);
    int wave = tid >> 6, lane = tid & 63;
    if (lane == 0) {
        #pragma unroll
        for (int pl = 0; pl < 8; ++pl) red[wave][pl] = part[pl];
    }
    __syncthreads();
    if (tid < 8) {
        float logit = red[0][tid] + red[1][tid] + bc2[0];
        out[p0 + tid] = 1.f / (1.f + expf(-logit));
    }
}

extern "C" void kernel_launch(void* const* d_in, const int* in_sizes, int n_in,
                              void* d_out, int out_size, void* d_ws, size_t ws_size,
                              hipStream_t stream) {
    // Revised model (round-3 evidence): float inputs are fp32, output fp32.
    const float* x   = (const float*)d_in[0];
    const int*   ei  = (const int*)d_in[1];
    const int*   post= (const int*)d_in[2];
    const float* W1  = (const float*)d_in[3];
    const float* b1  = (const float*)d_in[4];
    const float* W2  = (const float*)d_in[5];
    const float* b2  = (const float*)d_in[6];
    const float* Wc1 = (const float*)d_in[7];
    const float* bc1 = (const float*)d_in[8];
    const float* Wc2 = (const float*)d_in[9];
    const float* bc2 = (const float*)d_in[10];
    float* out = (float*)d_out;

    char* w = (char*)d_ws;
    size_t off = 0;
#define WS_ALLOC(type, name, count) \
    type* name = (type*)(w + off); \
    off += (((size_t)(count) * sizeof(type)) + 255) & ~(size_t)255;
    WS_ALLOC(float,          t0,   (size_t)N_NODES * D_IN)    // 51.2 MB
    WS_ALLOC(unsigned short, hbuf, (size_t)N_NODES * H_DIM)   // 51.2 MB (bf16)
    WS_ALLOC(float,          t1p,  (size_t)P_POST * H_DIM)    // 10.24 MB
    WS_ALLOC(float,          accP, (size_t)P_POST * H_DIM)    // 10.24 MB
    WS_ALLOC(int,            deg,    N_NODES)
    WS_ALLOC(float,          dinvb,  N_NODES)
    WS_ALLOC(int,            rowptr, N_NODES + 1)
    WS_ALLOC(int,            cursor, N_NODES + 1)
    WS_ALLOC(int,            csrsrc, E_EDGES)                 // 6.4 MB -> total ~131 MB
#undef WS_ALLOC
    (void)ws_size; (void)in_sizes; (void)n_in; (void)out_size;

    zero32_kernel<<<(P_POST * H_DIM + 255) / 256, 256, 0, stream>>>((unsigned int*)accP, P_POST * H_DIM);

    for (int s = 0; s < S_SNAP; ++s) {
        const int* srcs = ei + (size_t)s * 2 * E_EDGES;
        const int* dsts = srcs + E_EDGES;
        zero32_kernel<<<(N_NODES + 255) / 256, 256, 0, stream>>>((unsigned int*)deg, N_NODES);
        hist_kernel<<<E_EDGES / 256, 256, 0, stream>>>(dsts, deg);
        dinv_kernel<<<(N_NODES + 255) / 256, 256, 0, stream>>>(deg, dinvb);
        scan_kernel<<<1, 1024, 0, stream>>>(deg, rowptr, cursor);
        fill_kernel<<<E_EDGES / 256, 256, 0, stream>>>(srcs, dsts, cursor, csrsrc);
        // t0 = Ahat @ x    [N,128] fp32
        spmm_x_kernel<<<N_NODES / 4, 256, 0, stream>>>(x, dinvb, rowptr, csrsrc, t0);
        // h = relu(t0 @ W1 + b1)   [N,256] bf16
        dim3 g0((N_NODES + 63) / 64, 4);
        gemm_l0_kernel<<<g0, 256, 0, stream>>>(t0, W1, b1, hbuf, N_NODES, D_IN);
        // t1p = (Ahat @ h)[post]   [P,256] fp32
        spmm_h_post_kernel<<<P_POST / 4, 256, 0, stream>>>(hbuf, dinvb, rowptr, csrsrc, post, t1p);
        // accP += t1p @ W2 + b2 + h[post]
        dim3 g1((P_POST + 63) / 64, 4);
        gemm_l1_kernel<<<g1, 256, 0, stream>>>(t1p, W2, b2, hbuf, post, accP, P_POST);
    }
    classifier_kernel<<<P_POST / 8, 128, 0, stream>>>(accP, Wc1, bc1, Wc2, bc2, out);
}

// Round 5
// 2209.923 us; speedup vs baseline: 1.3939x; 1.3939x over previous
//
#include <hip/hip_runtime.h>
#include <math.h>

#define N_NODES 100000
#define E_EDGES 1600000
#define S_SNAP  4
#define D_IN    128
#define H_DIM   256
#define P_POST  10000
#define SCAN_NBLK ((N_NODES + 255) / 256)   // 391

// ---------- bf16 helpers (used ONLY for the h workspace buffer) ----------
__device__ __forceinline__ float bf2f(unsigned short u) {
    union { unsigned int i; float f; } v; v.i = ((unsigned int)u) << 16; return v.f;
}
__device__ __forceinline__ unsigned short f2bf(float f) {
    union { float f; unsigned int i; } v; v.f = f;
    unsigned int lsb = (v.i >> 16) & 1u;
    v.i += 0x7fffu + lsb;                 // round-nearest-even
    return (unsigned short)(v.i >> 16);
}

// ---------------- utility ----------------
__global__ void zero32_kernel(unsigned int* __restrict__ p, int n) {
    int i = blockIdx.x * blockDim.x + threadIdx.x;
    if (i < n) p[i] = 0u;
}

// ---------------- graph prep ----------------
__global__ void hist_kernel(const int* __restrict__ dst, int* __restrict__ deg) {
    int i = blockIdx.x * blockDim.x + threadIdx.x;
    if (i < E_EDGES) atomicAdd(&deg[dst[i]], 1);
}

__global__ void dinv_kernel(const int* __restrict__ deg, float* __restrict__ dinv) {
    int i = blockIdx.x * blockDim.x + threadIdx.x;
    if (i < N_NODES) dinv[i] = rsqrtf((float)(deg[i] + 1));  // +1 self-loop
}

// ---- multi-block exclusive scan (3 phases; replaces 231µs single-block scan) ----
__global__ __launch_bounds__(256) void scan_part_kernel(const int* __restrict__ deg,
        int* __restrict__ bsum) {
    __shared__ int red[4];
    int i = blockIdx.x * 256 + threadIdx.x;
    int s = (i < N_NODES) ? deg[i] : 0;
    #pragma unroll
    for (int off = 32; off > 0; off >>= 1) s += __shfl_down(s, off, 64);
    int wave = threadIdx.x >> 6, lane = threadIdx.x & 63;
    if (lane == 0) red[wave] = s;
    __syncthreads();
    if (threadIdx.x == 0) bsum[blockIdx.x] = red[0] + red[1] + red[2] + red[3];
}

__global__ __launch_bounds__(512) void scan_top_kernel(const int* __restrict__ bsum,
        int* __restrict__ boff) {
    __shared__ int s[512];
    int t = threadIdx.x;
    s[t] = (t < SCAN_NBLK) ? bsum[t] : 0;
    __syncthreads();
    for (int off = 1; off < 512; off <<= 1) {
        int v = (t >= off) ? s[t - off] : 0;
        __syncthreads();
        s[t] += v;
        __syncthreads();
    }
    if (t < SCAN_NBLK) boff[t] = (t == 0) ? 0 : s[t - 1];
}

__global__ __launch_bounds__(256) void scan_fin_kernel(const int* __restrict__ deg,
        const int* __restrict__ boff, int* __restrict__ rowptr, int* __restrict__ cursor) {
    __shared__ int s[256];
    int b = blockIdx.x, t = threadIdx.x;
    int i = b * 256 + t;
    int v = (i < N_NODES) ? deg[i] : 0;
    s[t] = v;
    __syncthreads();
    for (int off = 1; off < 256; off <<= 1) {
        int u = (t >= off) ? s[t - off] : 0;
        __syncthreads();
        s[t] += u;
        __syncthreads();
    }
    if (i < N_NODES) {
        int excl = boff[b] + s[t] - v;   // inclusive - self = exclusive
        rowptr[i] = excl; cursor[i] = excl;
    }
    if (i == 0) rowptr[N_NODES] = E_EDGES;   // total is a compile-time constant
}

__global__ void fill_kernel(const int* __restrict__ src, const int* __restrict__ dst,
        int* __restrict__ cursor, int* __restrict__ csrsrc) {
    int i = blockIdx.x * blockDim.x + threadIdx.x;
    if (i < E_EDGES) {
        int d = dst[i];
        int pos = atomicAdd(&cursor[d], 1);
        csrsrc[pos] = src[i];
    }
}

// ---------------- SpMM layer 0: t0 = Ahat @ x   (x fp32 [N,128] -> t0 fp32 [N,128]) ----
// one wave per dst row; lane holds 2 cols (float2 = 8B/lane, 512B coalesced per edge)
__global__ __launch_bounds__(256) void spmm_x_kernel(const float* __restrict__ x,
        const float* __restrict__ dinv, const int* __restrict__ rowptr,
        const int* __restrict__ csrsrc, float* __restrict__ t0) {
    int r = (blockIdx.x << 2) + (threadIdx.x >> 6);
    int lane = threadIdx.x & 63;
    int e0 = rowptr[r], e1 = rowptr[r + 1];
    float di = dinv[r];
    float ax = 0.f, ay = 0.f;
    const float2* xp = (const float2*)x;        // row stride 64 float2
    for (int e = e0; e < e1; ++e) {
        int s = csrsrc[e];
        float w = dinv[s] * di;
        float2 u = xp[(size_t)s * 64 + lane];
        ax = fmaf(u.x, w, ax);
        ay = fmaf(u.y, w, ay);
    }
    float2 u = xp[(size_t)r * 64 + lane];       // self loop, weight dinv^2
    float wd = di * di;
    ax = fmaf(u.x, wd, ax);
    ay = fmaf(u.y, wd, ay);
    ((float2*)t0)[(size_t)r * 64 + lane] = make_float2(ax, ay);
}

// ---------------- SpMM layer 1 (post rows only): t1p[p] = (Ahat @ h)[post[p]] ----------
// h bf16 [N,256]; lane holds 4 cols (ushort4 = 8B/lane, 512B coalesced per edge)
__global__ __launch_bounds__(256) void spmm_h_post_kernel(const unsigned short* __restrict__ h,
        const float* __restrict__ dinv, const int* __restrict__ rowptr,
        const int* __restrict__ csrsrc, const int* __restrict__ post,
        float* __restrict__ t1p) {
    int p = (blockIdx.x << 2) + (threadIdx.x >> 6);
    int lane = threadIdx.x & 63;
    int r = post[p];
    int e0 = rowptr[r], e1 = rowptr[r + 1];
    float di = dinv[r];
    float4 acc = make_float4(0.f, 0.f, 0.f, 0.f);
    const ushort4* hp = (const ushort4*)h;      // row stride 64 ushort4
    for (int e = e0; e < e1; ++e) {
        int s = csrsrc[e];
        float w = dinv[s] * di;
        ushort4 u = hp[(size_t)s * 64 + lane];
        acc.x = fmaf(bf2f(u.x), w, acc.x);
        acc.y = fmaf(bf2f(u.y), w, acc.y);
        acc.z = fmaf(bf2f(u.z), w, acc.z);
        acc.w = fmaf(bf2f(u.w), w, acc.w);
    }
    ushort4 u = hp[(size_t)r * 64 + lane];
    float wd = di * di;
    acc.x = fmaf(bf2f(u.x), wd, acc.x);
    acc.y = fmaf(bf2f(u.y), wd, acc.y);
    acc.z = fmaf(bf2f(u.z), wd, acc.z);
    acc.w = fmaf(bf2f(u.w), wd, acc.w);
    ((float4*)t1p)[(size_t)p * 64 + lane] = acc;
}

// ------- GEMM layer 0: h = relu(t0 @ W1 + b1)  (A fp32 [M,K], B fp32 [K,256], C bf16) ----
// 64x64 tile, 256 threads, 4x4/thread, BK=16
__global__ __launch_bounds__(256) void gemm_l0_kernel(const float* __restrict__ A,
        const float* __restrict__ B, const float* __restrict__ bias,
        unsigned short* __restrict__ C, int M, int K) {
    __shared__ float As[16][68];
    __shared__ float Bs[16][68];
    int tid = threadIdx.x;
    int tx = tid & 15, ty = tid >> 4;
    int m0 = blockIdx.x * 64, n0 = blockIdx.y * 64;
    int lar = tid >> 2;            // 0..63 A row in tile
    int lac = (tid & 3) << 2;      // 0,4,8,12 A col in tile
    int lbr = tid >> 4;            // 0..15 B row in tile
    int lbc = (tid & 15) << 2;     // 0..60 B col in tile
    float acc[4][4] = {};
    for (int kk = 0; kk < K; kk += 16) {
        float4 av = make_float4(0.f, 0.f, 0.f, 0.f);
        if (m0 + lar < M) av = *(const float4*)(A + (size_t)(m0 + lar) * K + kk + lac);
        float4 bv = *(const float4*)(B + (size_t)(kk + lbr) * 256 + n0 + lbc);
        __syncthreads();
        As[lac + 0][lar] = av.x; As[lac + 1][lar] = av.y;
        As[lac + 2][lar] = av.z; As[lac + 3][lar] = av.w;
        *(float4*)(&Bs[lbr][lbc]) = bv;
        __syncthreads();
        #pragma unroll
        for (int k = 0; k < 16; ++k) {
            float4 a4 = *(const float4*)(&As[k][ty << 2]);
            float4 b4 = *(const float4*)(&Bs[k][tx << 2]);
            float a[4] = {a4.x, a4.y, a4.z, a4.w};
            float b[4] = {b4.x, b4.y, b4.z, b4.w};
            #pragma unroll
            for (int i = 0; i < 4; ++i)
                #pragma unroll
                for (int j = 0; j < 4; ++j)
                    acc[i][j] = fmaf(a[i], b[j], acc[i][j]);
        }
    }
    int nb = n0 + (tx << 2);
    float4 bv = *(const float4*)(bias + nb);
    float bf[4] = {bv.x, bv.y, bv.z, bv.w};
    #pragma unroll
    for (int i = 0; i < 4; ++i) {
        int m = m0 + (ty << 2) + i;
        if (m < M) {
            ushort4 o;
            o.x = f2bf(fmaxf(acc[i][0] + bf[0], 0.f));
            o.y = f2bf(fmaxf(acc[i][1] + bf[1], 0.f));
            o.z = f2bf(fmaxf(acc[i][2] + bf[2], 0.f));
            o.w = f2bf(fmaxf(acc[i][3] + bf[3], 0.f));
            *(ushort4*)(C + (size_t)m * 256 + nb) = o;
        }
    }
}

// ------- GEMM layer 1 (post rows): accP += t1p @ W2 + b2 + h[post]  (accP fp32 [P,256]) ---
__global__ __launch_bounds__(256) void gemm_l1_kernel(const float* __restrict__ A,
        const float* __restrict__ B, const float* __restrict__ b2,
        const unsigned short* __restrict__ h, const int* __restrict__ post,
        float* __restrict__ accP, int M) {
    __shared__ float As[16][68];
    __shared__ float Bs[16][68];
    int tid = threadIdx.x;
    int tx = tid & 15, ty = tid >> 4;
    int m0 = blockIdx.x * 64, n0 = blockIdx.y * 64;
    int lar = tid >> 2;
    int lac = (tid & 3) << 2;
    int lbr = tid >> 4;
    int lbc = (tid & 15) << 2;
    float acc[4][4] = {};
    for (int kk = 0; kk < 256; kk += 16) {
        float4 av = make_float4(0.f, 0.f, 0.f, 0.f);
        if (m0 + lar < M) av = *(const float4*)(A + (size_t)(m0 + lar) * 256 + kk + lac);
        float4 bv = *(const float4*)(B + (size_t)(kk + lbr) * 256 + n0 + lbc);
        __syncthreads();
        As[lac + 0][lar] = av.x; As[lac + 1][lar] = av.y;
        As[lac + 2][lar] = av.z; As[lac + 3][lar] = av.w;
        *(float4*)(&Bs[lbr][lbc]) = bv;
        __syncthreads();
        #pragma unroll
        for (int k = 0; k < 16; ++k) {
            float4 a4 = *(const float4*)(&As[k][ty << 2]);
            float4 b4 = *(const float4*)(&Bs[k][tx << 2]);
            float a[4] = {a4.x, a4.y, a4.z, a4.w};
            float b[4] = {b4.x, b4.y, b4.z, b4.w};
            #pragma unroll
            for (int i = 0; i < 4; ++i)
                #pragma unroll
                for (int j = 0; j < 4; ++j)
                    acc[i][j] = fmaf(a[i], b[j], acc[i][j]);
        }
    }
    int nb = n0 + (tx << 2);
    float4 bv = *(const float4*)(b2 + nb);
    float bf[4] = {bv.x, bv.y, bv.z, bv.w};
    #pragma unroll
    for (int i = 0; i < 4; ++i) {
        int m = m0 + (ty << 2) + i;
        if (m < M) {
            int node = post[m];
            ushort4 hr = *(const ushort4*)(h + (size_t)node * 256 + nb);
            float4 a = *(float4*)(accP + (size_t)m * 256 + nb);
            a.x += acc[i][0] + bf[0] + bf2f(hr.x);
            a.y += acc[i][1] + bf[1] + bf2f(hr.y);
            a.z += acc[i][2] + bf[2] + bf2f(hr.z);
            a.w += acc[i][3] + bf[3] + bf2f(hr.w);
            *(float4*)(accP + (size_t)m * 256 + nb) = a;
        }
    }
}

// ---------------- classifier: sigmoid(relu(accP/4 @ Wc1 + bc1) @ Wc2 + bc2) ----------------
__global__ __launch_bounds__(128) void classifier_kernel(const float* __restrict__ accP,
        const float* __restrict__ Wc1, const float* __restrict__ bc1,
        const float* __restrict__ Wc2, const float* __restrict__ bc2,
        float* __restrict__ out) {
    __shared__ float arow[8][256];
    __shared__ float red[2][8];
    int p0 = blockIdx.x << 3;
    int tid = threadIdx.x;     // 128 threads; tid == hidden col
    for (int idx = tid; idx < 8 * 256; idx += 128) {
        int pl = idx >> 8, k = idx & 255;
        arow[pl][k] = 0.25f * accP[(size_t)(p0 + pl) * 256 + k];  // mean over S=4
    }
    __syncthreads();
    float s[8];
    float b = bc1[tid];
    #pragma unroll
    for (int pl = 0; pl < 8; ++pl) s[pl] = b;
    for (int k = 0; k < 256; ++k) {
        float wv = Wc1[k * 128 + tid];
        #pragma unroll
        for (int pl = 0; pl < 8; ++pl) s[pl] = fmaf(arow[pl][k], wv, s[pl]);
    }
    float wc2 = Wc2[tid];
    float part[8];
    #pragma unroll
    for (int pl = 0; pl < 8; ++pl) part[pl] = fmaxf(s[pl], 0.f) * wc2;
    #pragma unroll
    for (int off = 32; off > 0; off >>= 1)
        #pragma unroll
        for (int pl = 0; pl < 8; ++pl) part[pl] += __shfl_down(part[pl], off, 64);
    int wave = tid >> 6, lane = tid & 63;
    if (lane == 0) {
        #pragma unroll
        for (int pl = 0; pl < 8; ++pl) red[wave][pl] = part[pl];
    }
    __syncthreads();
    if (tid < 8) {
        float logit = red[0][tid] + red[1][tid] + bc2[0];
        out[p0 + tid] = 1.f / (1.f + expf(-logit));
    }
}

extern "C" void kernel_launch(void* const* d_in, const int* in_sizes, int n_in,
                              void* d_out, int out_size, void* d_ws, size_t ws_size,
                              hipStream_t stream) {
    const float* x   = (const float*)d_in[0];
    const int*   ei  = (const int*)d_in[1];
    const int*   post= (const int*)d_in[2];
    const float* W1  = (const float*)d_in[3];
    const float* b1  = (const float*)d_in[4];
    const float* W2  = (const float*)d_in[5];
    const float* b2  = (const float*)d_in[6];
    const float* Wc1 = (const float*)d_in[7];
    const float* bc1 = (const float*)d_in[8];
    const float* Wc2 = (const float*)d_in[9];
    const float* bc2 = (const float*)d_in[10];
    float* out = (float*)d_out;

    char* w = (char*)d_ws;
    size_t off = 0;
#define WS_ALLOC(type, name, count) \
    type* name = (type*)(w + off); \
    off += (((size_t)(count) * sizeof(type)) + 255) & ~(size_t)255;
    WS_ALLOC(float,          t0,   (size_t)N_NODES * D_IN)    // 51.2 MB
    WS_ALLOC(unsigned short, hbuf, (size_t)N_NODES * H_DIM)   // 51.2 MB (bf16)
    WS_ALLOC(float,          t1p,  (size_t)P_POST * H_DIM)    // 10.24 MB
    WS_ALLOC(float,          accP, (size_t)P_POST * H_DIM)    // 10.24 MB
    WS_ALLOC(int,            deg,    N_NODES)
    WS_ALLOC(float,          dinvb,  N_NODES)
    WS_ALLOC(int,            rowptr, N_NODES + 1)
    WS_ALLOC(int,            cursor, N_NODES + 1)
    WS_ALLOC(int,            csrsrc, E_EDGES)                 // 6.4 MB -> total ~131 MB
    WS_ALLOC(int,            bsum,   SCAN_NBLK)
    WS_ALLOC(int,            boff,   SCAN_NBLK)
#undef WS_ALLOC
    (void)ws_size; (void)in_sizes; (void)n_in; (void)out_size;

    zero32_kernel<<<(P_POST * H_DIM + 255) / 256, 256, 0, stream>>>((unsigned int*)accP, P_POST * H_DIM);

    for (int s = 0; s < S_SNAP; ++s) {
        const int* srcs = ei + (size_t)s * 2 * E_EDGES;
        const int* dsts = srcs + E_EDGES;
        zero32_kernel<<<(N_NODES + 255) / 256, 256, 0, stream>>>((unsigned int*)deg, N_NODES);
        hist_kernel<<<E_EDGES / 256, 256, 0, stream>>>(dsts, deg);
        dinv_kernel<<<(N_NODES + 255) / 256, 256, 0, stream>>>(deg, dinvb);
        // multi-block exclusive scan: deg -> rowptr/cursor
        scan_part_kernel<<<SCAN_NBLK, 256, 0, stream>>>(deg, bsum);
        scan_top_kernel<<<1, 512, 0, stream>>>(bsum, boff);
        scan_fin_kernel<<<SCAN_NBLK, 256, 0, stream>>>(deg, boff, rowptr, cursor);
        fill_kernel<<<E_EDGES / 256, 256, 0, stream>>>(srcs, dsts, cursor, csrsrc);
        // t0 = Ahat @ x    [N,128] fp32
        spmm_x_kernel<<<N_NODES / 4, 256, 0, stream>>>(x, dinvb, rowptr, csrsrc, t0);
        // h = relu(t0 @ W1 + b1)   [N,256] bf16
        dim3 g0((N_NODES + 63) / 64, 4);
        gemm_l0_kernel<<<g0, 256, 0, stream>>>(t0, W1, b1, hbuf, N_NODES, D_IN);
        // t1p = (Ahat @ h)[post]   [P,256] fp32
        spmm_h_post_kernel<<<P_POST / 4, 256, 0, stream>>>(hbuf, dinvb, rowptr, csrsrc, post, t1p);
        // accP += t1p @ W2 + b2 + h[post]
        dim3 g1((P_POST + 63) / 64, 4);
        gemm_l1_kernel<<<g1, 256, 0, stream>>>(t1p, W2, b2, hbuf, post, accP, P_POST);
    }
    classifier_kernel<<<P_POST / 8, 128, 0, stream>>>(accP, Wc1, bc1, Wc2, bc2, out);
}

// Round 6
// 1652.957 us; speedup vs baseline: 1.8635x; 1.3370x over previous
//
#include <hip/hip_runtime.h>
#include <math.h>

#define N_NODES 100000
#define E_EDGES 1600000
#define S_SNAP  4
#define D_IN    128
#define H_DIM   256
#define P_POST  10000
#define SCAN_NBLK ((N_NODES + 255) / 256)   // 391

// ---------- bf16 helpers ----------
__device__ __forceinline__ float bf2f(unsigned short u) {
    union { unsigned int i; float f; } v; v.i = ((unsigned int)u) << 16; return v.f;
}
__device__ __forceinline__ unsigned short f2bf(float f) {
    union { float f; unsigned int i; } v; v.f = f;
    unsigned int lsb = (v.i >> 16) & 1u;
    v.i += 0x7fffu + lsb;                 // round-nearest-even
    return (unsigned short)(v.i >> 16);
}

// ---------------- utility ----------------
__global__ void zero32_kernel(unsigned int* __restrict__ p, int n) {
    int i = blockIdx.x * blockDim.x + threadIdx.x;
    if (i < n) p[i] = 0u;
}

// ---------------- graph prep ----------------
__global__ void hist_kernel(const int* __restrict__ dst, int* __restrict__ deg) {
    int i = blockIdx.x * blockDim.x + threadIdx.x;
    if (i < E_EDGES) atomicAdd(&deg[dst[i]], 1);
}

__global__ void dinv_kernel(const int* __restrict__ deg, float* __restrict__ dinv) {
    int i = blockIdx.x * blockDim.x + threadIdx.x;
    if (i < N_NODES) dinv[i] = rsqrtf((float)(deg[i] + 1));  // +1 self-loop
}

__global__ __launch_bounds__(256) void scan_part_kernel(const int* __restrict__ deg,
        int* __restrict__ bsum) {
    __shared__ int red[4];
    int i = blockIdx.x * 256 + threadIdx.x;
    int s = (i < N_NODES) ? deg[i] : 0;
    #pragma unroll
    for (int off = 32; off > 0; off >>= 1) s += __shfl_down(s, off, 64);
    int wave = threadIdx.x >> 6, lane = threadIdx.x & 63;
    if (lane == 0) red[wave] = s;
    __syncthreads();
    if (threadIdx.x == 0) bsum[blockIdx.x] = red[0] + red[1] + red[2] + red[3];
}

__global__ __launch_bounds__(512) void scan_top_kernel(const int* __restrict__ bsum,
        int* __restrict__ boff) {
    __shared__ int s[512];
    int t = threadIdx.x;
    s[t] = (t < SCAN_NBLK) ? bsum[t] : 0;
    __syncthreads();
    for (int off = 1; off < 512; off <<= 1) {
        int v = (t >= off) ? s[t - off] : 0;
        __syncthreads();
        s[t] += v;
        __syncthreads();
    }
    if (t < SCAN_NBLK) boff[t] = (t == 0) ? 0 : s[t - 1];
}

__global__ __launch_bounds__(256) void scan_fin_kernel(const int* __restrict__ deg,
        const int* __restrict__ boff, int* __restrict__ rowptr, int* __restrict__ cursor) {
    __shared__ int s[256];
    int b = blockIdx.x, t = threadIdx.x;
    int i = b * 256 + t;
    int v = (i < N_NODES) ? deg[i] : 0;
    s[t] = v;
    __syncthreads();
    for (int off = 1; off < 256; off <<= 1) {
        int u = (t >= off) ? s[t - off] : 0;
        __syncthreads();
        s[t] += u;
        __syncthreads();
    }
    if (i < N_NODES) {
        int excl = boff[b] + s[t] - v;
        rowptr[i] = excl; cursor[i] = excl;
    }
    if (i == 0) rowptr[N_NODES] = E_EDGES;
}

__global__ void fill_kernel(const int* __restrict__ src, const int* __restrict__ dst,
        int* __restrict__ cursor, int* __restrict__ csrsrc) {
    int i = blockIdx.x * blockDim.x + threadIdx.x;
    if (i < E_EDGES) {
        int d = dst[i];
        int pos = atomicAdd(&cursor[d], 1);
        csrsrc[pos] = src[i];
    }
}

// ------- GEMM (once per call): xw1 = x @ W1, bf16 out, no epilogue -------
// 64x64 tile, 256 threads, 4x4/thread, BK=16
__global__ __launch_bounds__(256) void gemm_xw1_kernel(const float* __restrict__ A,
        const float* __restrict__ B, unsigned short* __restrict__ C, int M, int K) {
    __shared__ float As[16][68];
    __shared__ float Bs[16][68];
    int tid = threadIdx.x;
    int tx = tid & 15, ty = tid >> 4;
    int m0 = blockIdx.x * 64, n0 = blockIdx.y * 64;
    int lar = tid >> 2;
    int lac = (tid & 3) << 2;
    int lbr = tid >> 4;
    int lbc = (tid & 15) << 2;
    float acc[4][4] = {};
    for (int kk = 0; kk < K; kk += 16) {
        float4 av = make_float4(0.f, 0.f, 0.f, 0.f);
        if (m0 + lar < M) av = *(const float4*)(A + (size_t)(m0 + lar) * K + kk + lac);
        float4 bv = *(const float4*)(B + (size_t)(kk + lbr) * 256 + n0 + lbc);
        __syncthreads();
        As[lac + 0][lar] = av.x; As[lac + 1][lar] = av.y;
        As[lac + 2][lar] = av.z; As[lac + 3][lar] = av.w;
        *(float4*)(&Bs[lbr][lbc]) = bv;
        __syncthreads();
        #pragma unroll
        for (int k = 0; k < 16; ++k) {
            float4 a4 = *(const float4*)(&As[k][ty << 2]);
            float4 b4 = *(const float4*)(&Bs[k][tx << 2]);
            float a[4] = {a4.x, a4.y, a4.z, a4.w};
            float b[4] = {b4.x, b4.y, b4.z, b4.w};
            #pragma unroll
            for (int i = 0; i < 4; ++i)
                #pragma unroll
                for (int j = 0; j < 4; ++j)
                    acc[i][j] = fmaf(a[i], b[j], acc[i][j]);
        }
    }
    int nb = n0 + (tx << 2);
    #pragma unroll
    for (int i = 0; i < 4; ++i) {
        int m = m0 + (ty << 2) + i;
        if (m < M) {
            ushort4 o;
            o.x = f2bf(acc[i][0]); o.y = f2bf(acc[i][1]);
            o.z = f2bf(acc[i][2]); o.w = f2bf(acc[i][3]);
            *(ushort4*)(C + (size_t)m * 256 + nb) = o;
        }
    }
}

// ------- SpMM layer 0 (fused bias+relu): h[r] = relu(sum_e w*xw1[src] + di^2*xw1[r] + b1) ---
// one wave per dst row; lane = 4 cols (ushort4, 512B/edge); 4-way edge unroll for MLP
__global__ __launch_bounds__(256) void spmm_l0_kernel(const unsigned short* __restrict__ xw1,
        const float* __restrict__ dinv, const int* __restrict__ rowptr,
        const int* __restrict__ csrsrc, const float* __restrict__ b1,
        unsigned short* __restrict__ h) {
    int r = (blockIdx.x << 2) + (threadIdx.x >> 6);
    int lane = threadIdx.x & 63;
    int e0 = rowptr[r], e1 = rowptr[r + 1];
    float di = dinv[r];
    float4 acc = make_float4(0.f, 0.f, 0.f, 0.f);
    const ushort4* tp = (const ushort4*)xw1;    // row stride 64 ushort4
    int e = e0;
    for (; e + 4 <= e1; e += 4) {
        int s0 = csrsrc[e], s1 = csrsrc[e + 1], s2 = csrsrc[e + 2], s3 = csrsrc[e + 3];
        float w0 = dinv[s0] * di, w1 = dinv[s1] * di, w2 = dinv[s2] * di, w3 = dinv[s3] * di;
        ushort4 u0 = tp[(size_t)s0 * 64 + lane];
        ushort4 u1 = tp[(size_t)s1 * 64 + lane];
        ushort4 u2 = tp[(size_t)s2 * 64 + lane];
        ushort4 u3 = tp[(size_t)s3 * 64 + lane];
        acc.x = fmaf(bf2f(u0.x), w0, acc.x); acc.y = fmaf(bf2f(u0.y), w0, acc.y);
        acc.z = fmaf(bf2f(u0.z), w0, acc.z); acc.w = fmaf(bf2f(u0.w), w0, acc.w);
        acc.x = fmaf(bf2f(u1.x), w1, acc.x); acc.y = fmaf(bf2f(u1.y), w1, acc.y);
        acc.z = fmaf(bf2f(u1.z), w1, acc.z); acc.w = fmaf(bf2f(u1.w), w1, acc.w);
        acc.x = fmaf(bf2f(u2.x), w2, acc.x); acc.y = fmaf(bf2f(u2.y), w2, acc.y);
        acc.z = fmaf(bf2f(u2.z), w2, acc.z); acc.w = fmaf(bf2f(u2.w), w2, acc.w);
        acc.x = fmaf(bf2f(u3.x), w3, acc.x); acc.y = fmaf(bf2f(u3.y), w3, acc.y);
        acc.z = fmaf(bf2f(u3.z), w3, acc.z); acc.w = fmaf(bf2f(u3.w), w3, acc.w);
    }
    for (; e < e1; ++e) {
        int s = csrsrc[e];
        float wv = dinv[s] * di;
        ushort4 u = tp[(size_t)s * 64 + lane];
        acc.x = fmaf(bf2f(u.x), wv, acc.x); acc.y = fmaf(bf2f(u.y), wv, acc.y);
        acc.z = fmaf(bf2f(u.z), wv, acc.z); acc.w = fmaf(bf2f(u.w), wv, acc.w);
    }
    ushort4 us = tp[(size_t)r * 64 + lane];     // self loop
    float wd = di * di;
    float4 bb = ((const float4*)b1)[lane];
    ushort4 o;
    o.x = f2bf(fmaxf(fmaf(bf2f(us.x), wd, acc.x) + bb.x, 0.f));
    o.y = f2bf(fmaxf(fmaf(bf2f(us.y), wd, acc.y) + bb.y, 0.f));
    o.z = f2bf(fmaxf(fmaf(bf2f(us.z), wd, acc.z) + bb.z, 0.f));
    o.w = f2bf(fmaxf(fmaf(bf2f(us.w), wd, acc.w) + bb.w, 0.f));
    ((ushort4*)h)[(size_t)r * 64 + lane] = o;
}

// ---------------- SpMM layer 1 (post rows only): t1p[p] = (Ahat @ h)[post[p]] ----------
__global__ __launch_bounds__(256) void spmm_h_post_kernel(const unsigned short* __restrict__ h,
        const float* __restrict__ dinv, const int* __restrict__ rowptr,
        const int* __restrict__ csrsrc, const int* __restrict__ post,
        float* __restrict__ t1p) {
    int p = (blockIdx.x << 2) + (threadIdx.x >> 6);
    int lane = threadIdx.x & 63;
    int r = post[p];
    int e0 = rowptr[r], e1 = rowptr[r + 1];
    float di = dinv[r];
    float4 acc = make_float4(0.f, 0.f, 0.f, 0.f);
    const ushort4* hp = (const ushort4*)h;
    int e = e0;
    for (; e + 4 <= e1; e += 4) {
        int s0 = csrsrc[e], s1 = csrsrc[e + 1], s2 = csrsrc[e + 2], s3 = csrsrc[e + 3];
        float w0 = dinv[s0] * di, w1 = dinv[s1] * di, w2 = dinv[s2] * di, w3 = dinv[s3] * di;
        ushort4 u0 = hp[(size_t)s0 * 64 + lane];
        ushort4 u1 = hp[(size_t)s1 * 64 + lane];
        ushort4 u2 = hp[(size_t)s2 * 64 + lane];
        ushort4 u3 = hp[(size_t)s3 * 64 + lane];
        acc.x = fmaf(bf2f(u0.x), w0, acc.x); acc.y = fmaf(bf2f(u0.y), w0, acc.y);
        acc.z = fmaf(bf2f(u0.z), w0, acc.z); acc.w = fmaf(bf2f(u0.w), w0, acc.w);
        acc.x = fmaf(bf2f(u1.x), w1, acc.x); acc.y = fmaf(bf2f(u1.y), w1, acc.y);
        acc.z = fmaf(bf2f(u1.z), w1, acc.z); acc.w = fmaf(bf2f(u1.w), w1, acc.w);
        acc.x = fmaf(bf2f(u2.x), w2, acc.x); acc.y = fmaf(bf2f(u2.y), w2, acc.y);
        acc.z = fmaf(bf2f(u2.z), w2, acc.z); acc.w = fmaf(bf2f(u2.w), w2, acc.w);
        acc.x = fmaf(bf2f(u3.x), w3, acc.x); acc.y = fmaf(bf2f(u3.y), w3, acc.y);
        acc.z = fmaf(bf2f(u3.z), w3, acc.z); acc.w = fmaf(bf2f(u3.w), w3, acc.w);
    }
    for (; e < e1; ++e) {
        int s = csrsrc[e];
        float wv = dinv[s] * di;
        ushort4 u = hp[(size_t)s * 64 + lane];
        acc.x = fmaf(bf2f(u.x), wv, acc.x); acc.y = fmaf(bf2f(u.y), wv, acc.y);
        acc.z = fmaf(bf2f(u.z), wv, acc.z); acc.w = fmaf(bf2f(u.w), wv, acc.w);
    }
    ushort4 u = hp[(size_t)r * 64 + lane];
    float wd = di * di;
    acc.x = fmaf(bf2f(u.x), wd, acc.x);
    acc.y = fmaf(bf2f(u.y), wd, acc.y);
    acc.z = fmaf(bf2f(u.z), wd, acc.z);
    acc.w = fmaf(bf2f(u.w), wd, acc.w);
    ((float4*)t1p)[(size_t)p * 64 + lane] = acc;
}

// ------- GEMM layer 1 (post rows): accP += t1p @ W2 + b2 + h[post] -------
__global__ __launch_bounds__(256) void gemm_l1_kernel(const float* __restrict__ A,
        const float* __restrict__ B, const float* __restrict__ b2,
        const unsigned short* __restrict__ h, const int* __restrict__ post,
        float* __restrict__ accP, int M) {
    __shared__ float As[16][68];
    __shared__ float Bs[16][68];
    int tid = threadIdx.x;
    int tx = tid & 15, ty = tid >> 4;
    int m0 = blockIdx.x * 64, n0 = blockIdx.y * 64;
    int lar = tid >> 2;
    int lac = (tid & 3) << 2;
    int lbr = tid >> 4;
    int lbc = (tid & 15) << 2;
    float acc[4][4] = {};
    for (int kk = 0; kk < 256; kk += 16) {
        float4 av = make_float4(0.f, 0.f, 0.f, 0.f);
        if (m0 + lar < M) av = *(const float4*)(A + (size_t)(m0 + lar) * 256 + kk + lac);
        float4 bv = *(const float4*)(B + (size_t)(kk + lbr) * 256 + n0 + lbc);
        __syncthreads();
        As[lac + 0][lar] = av.x; As[lac + 1][lar] = av.y;
        As[lac + 2][lar] = av.z; As[lac + 3][lar] = av.w;
        *(float4*)(&Bs[lbr][lbc]) = bv;
        __syncthreads();
        #pragma unroll
        for (int k = 0; k < 16; ++k) {
            float4 a4 = *(const float4*)(&As[k][ty << 2]);
            float4 b4 = *(const float4*)(&Bs[k][tx << 2]);
            float a[4] = {a4.x, a4.y, a4.z, a4.w};
            float b[4] = {b4.x, b4.y, b4.z, b4.w};
            #pragma unroll
            for (int i = 0; i < 4; ++i)
                #pragma unroll
                for (int j = 0; j < 4; ++j)
                    acc[i][j] = fmaf(a[i], b[j], acc[i][j]);
        }
    }
    int nb = n0 + (tx << 2);
    float4 bv = *(const float4*)(b2 + nb);
    float bf[4] = {bv.x, bv.y, bv.z, bv.w};
    #pragma unroll
    for (int i = 0; i < 4; ++i) {
        int m = m0 + (ty << 2) + i;
        if (m < M) {
            int node = post[m];
            ushort4 hr = *(const ushort4*)(h + (size_t)node * 256 + nb);
            float4 a = *(float4*)(accP + (size_t)m * 256 + nb);
            a.x += acc[i][0] + bf[0] + bf2f(hr.x);
            a.y += acc[i][1] + bf[1] + bf2f(hr.y);
            a.z += acc[i][2] + bf[2] + bf2f(hr.z);
            a.w += acc[i][3] + bf[3] + bf2f(hr.w);
            *(float4*)(accP + (size_t)m * 256 + nb) = a;
        }
    }
}

// ---------------- classifier ----------------
__global__ __launch_bounds__(128) void classifier_kernel(const float* __restrict__ accP,
        const float* __restrict__ Wc1, const float* __restrict__ bc1,
        const float* __restrict__ Wc2, const float* __restrict__ bc2,
        float* __restrict__ out) {
    __shared__ float arow[8][256];
    __shared__ float red[2][8];
    int p0 = blockIdx.x << 3;
    int tid = threadIdx.x;
    for (int idx = tid; idx < 8 * 256; idx += 128) {
        int pl = idx >> 8, k = idx & 255;
        arow[pl][k] = 0.25f * accP[(size_t)(p0 + pl) * 256 + k];
    }
    __syncthreads();
    float s[8];
    float b = bc1[tid];
    #pragma unroll
    for (int pl = 0; pl < 8; ++pl) s[pl] = b;
    for (int k = 0; k < 256; ++k) {
        float wv = Wc1[k * 128 + tid];
        #pragma unroll
        for (int pl = 0; pl < 8; ++pl) s[pl] = fmaf(arow[pl][k], wv, s[pl]);
    }
    float wc2 = Wc2[tid];
    float part[8];
    #pragma unroll
    for (int pl = 0; pl < 8; ++pl) part[pl] = fmaxf(s[pl], 0.f) * wc2;
    #pragma unroll
    for (int off = 32; off > 0; off >>= 1)
        #pragma unroll
        for (int pl = 0; pl < 8; ++pl) part[pl] += __shfl_down(part[pl], off, 64);
    int wave = tid >> 6, lane = tid & 63;
    if (lane == 0) {
        #pragma unroll
        for (int pl = 0; pl < 8; ++pl) red[wave][pl] = part[pl];
    }
    __syncthreads();
    if (tid < 8) {
        float logit = red[0][tid] + red[1][tid] + bc2[0];
        out[p0 + tid] = 1.f / (1.f + expf(-logit));
    }
}

extern "C" void kernel_launch(void* const* d_in, const int* in_sizes, int n_in,
                              void* d_out, int out_size, void* d_ws, size_t ws_size,
                              hipStream_t stream) {
    const float* x   = (const float*)d_in[0];
    const int*   ei  = (const int*)d_in[1];
    const int*   post= (const int*)d_in[2];
    const float* W1  = (const float*)d_in[3];
    const float* b1  = (const float*)d_in[4];
    const float* W2  = (const float*)d_in[5];
    const float* b2  = (const float*)d_in[6];
    const float* Wc1 = (const float*)d_in[7];
    const float* bc1 = (const float*)d_in[8];
    const float* Wc2 = (const float*)d_in[9];
    const float* bc2 = (const float*)d_in[10];
    float* out = (float*)d_out;

    char* w = (char*)d_ws;
    size_t off = 0;
#define WS_ALLOC(type, name, count) \
    type* name = (type*)(w + off); \
    off += (((size_t)(count) * sizeof(type)) + 255) & ~(size_t)255;
    WS_ALLOC(unsigned short, xw1,  (size_t)N_NODES * H_DIM)   // 51.2 MB (bf16)
    WS_ALLOC(unsigned short, hbuf, (size_t)N_NODES * H_DIM)   // 51.2 MB (bf16)
    WS_ALLOC(float,          t1p,  (size_t)P_POST * H_DIM)    // 10.24 MB
    WS_ALLOC(float,          accP, (size_t)P_POST * H_DIM)    // 10.24 MB
    WS_ALLOC(int,            deg,    N_NODES)
    WS_ALLOC(float,          dinvb,  N_NODES)
    WS_ALLOC(int,            rowptr, N_NODES + 1)
    WS_ALLOC(int,            cursor, N_NODES + 1)
    WS_ALLOC(int,            csrsrc, E_EDGES)                 // 6.4 MB -> total ~131 MB
    WS_ALLOC(int,            bsum,   SCAN_NBLK)
    WS_ALLOC(int,            boff,   SCAN_NBLK)
#undef WS_ALLOC
    (void)ws_size; (void)in_sizes; (void)n_in; (void)out_size;

    zero32_kernel<<<(P_POST * H_DIM + 255) / 256, 256, 0, stream>>>((unsigned int*)accP, P_POST * H_DIM);

    // xw1 = x @ W1 once per call (snapshot-invariant); bias+relu fused into spmm_l0
    dim3 gg((N_NODES + 63) / 64, 4);
    gemm_xw1_kernel<<<gg, 256, 0, stream>>>(x, W1, xw1, N_NODES, D_IN);

    for (int s = 0; s < S_SNAP; ++s) {
        const int* srcs = ei + (size_t)s * 2 * E_EDGES;
        const int* dsts = srcs + E_EDGES;
        zero32_kernel<<<(N_NODES + 255) / 256, 256, 0, stream>>>((unsigned int*)deg, N_NODES);
        hist_kernel<<<E_EDGES / 256, 256, 0, stream>>>(dsts, deg);
        dinv_kernel<<<(N_NODES + 255) / 256, 256, 0, stream>>>(deg, dinvb);
        scan_part_kernel<<<SCAN_NBLK, 256, 0, stream>>>(deg, bsum);
        scan_top_kernel<<<1, 512, 0, stream>>>(bsum, boff);
        scan_fin_kernel<<<SCAN_NBLK, 256, 0, stream>>>(deg, boff, rowptr, cursor);
        fill_kernel<<<E_EDGES / 256, 256, 0, stream>>>(srcs, dsts, cursor, csrsrc);
        // h = relu(Ahat @ xw1 + b1)   [N,256] bf16  (fused epilogue)
        spmm_l0_kernel<<<N_NODES / 4, 256, 0, stream>>>(xw1, dinvb, rowptr, csrsrc, b1, hbuf);
        // t1p = (Ahat @ h)[post]   [P,256] fp32
        spmm_h_post_kernel<<<P_POST / 4, 256, 0, stream>>>(hbuf, dinvb, rowptr, csrsrc, post, t1p);
        // accP += t1p @ W2 + b2 + h[post]
        dim3 g1((P_POST + 63) / 64, 4);
        gemm_l1_kernel<<<g1, 256, 0, stream>>>(t1p, W2, b2, hbuf, post, accP, P_POST);
    }
    classifier_kernel<<<P_POST / 8, 128, 0, stream>>>(accP, Wc1, bc1, Wc2, bc2, out);
}

// Round 7
// 1376.644 us; speedup vs baseline: 2.2376x; 1.2007x over previous
//
#include <hip/hip_runtime.h>
#include <math.h>

#define N_NODES 100000
#define E_EDGES 1600000
#define S_SNAP  4
#define D_IN    128
#define H_DIM   256
#define P_POST  10000
#define SCAN_NBLK ((N_NODES + 255) / 256)   // 391
#define NBIN 8
#define BIN_W (N_NODES / NBIN)              // 12500
#define FILL_CHUNK 2048
#define FILL_NCHUNK ((E_EDGES + FILL_CHUNK - 1) / FILL_CHUNK)   // 782

// ---------- bf16 helpers ----------
__device__ __forceinline__ float bf2f(unsigned short u) {
    union { unsigned int i; float f; } v; v.i = ((unsigned int)u) << 16; return v.f;
}
__device__ __forceinline__ unsigned short f2bf(float f) {
    union { float f; unsigned int i; } v; v.f = f;
    unsigned int lsb = (v.i >> 16) & 1u;
    v.i += 0x7fffu + lsb;                 // round-nearest-even
    return (unsigned short)(v.i >> 16);
}

// ---------------- utility ----------------
__global__ void zero32_kernel(unsigned int* __restrict__ p, int n) {
    int i = blockIdx.x * blockDim.x + threadIdx.x;
    if (i < n) p[i] = 0u;
}

// ---------------- graph prep ----------------
// hist also records each edge's within-row slot (atomic return value) -> fill needs no atomics
__global__ void hist_kernel(const int* __restrict__ dst, int* __restrict__ deg,
        int* __restrict__ slot) {
    int i = blockIdx.x * blockDim.x + threadIdx.x;
    if (i < E_EDGES) slot[i] = atomicAdd(&deg[dst[i]], 1);
}

__global__ void dinv_kernel(const int* __restrict__ deg, float* __restrict__ dinv) {
    int i = blockIdx.x * blockDim.x + threadIdx.x;
    if (i < N_NODES) dinv[i] = rsqrtf((float)(deg[i] + 1));  // +1 self-loop
}

__global__ __launch_bounds__(256) void scan_part_kernel(const int* __restrict__ deg,
        int* __restrict__ bsum) {
    __shared__ int red[4];
    int i = blockIdx.x * 256 + threadIdx.x;
    int s = (i < N_NODES) ? deg[i] : 0;
    #pragma unroll
    for (int off = 32; off > 0; off >>= 1) s += __shfl_down(s, off, 64);
    int wave = threadIdx.x >> 6, lane = threadIdx.x & 63;
    if (lane == 0) red[wave] = s;
    __syncthreads();
    if (threadIdx.x == 0) bsum[blockIdx.x] = red[0] + red[1] + red[2] + red[3];
}

__global__ __launch_bounds__(512) void scan_top_kernel(const int* __restrict__ bsum,
        int* __restrict__ boff) {
    __shared__ int s[512];
    int t = threadIdx.x;
    s[t] = (t < SCAN_NBLK) ? bsum[t] : 0;
    __syncthreads();
    for (int off = 1; off < 512; off <<= 1) {
        int v = (t >= off) ? s[t - off] : 0;
        __syncthreads();
        s[t] += v;
        __syncthreads();
    }
    if (t < SCAN_NBLK) boff[t] = (t == 0) ? 0 : s[t - 1];
}

__global__ __launch_bounds__(256) void scan_fin_kernel(const int* __restrict__ deg,
        const int* __restrict__ boff, int* __restrict__ rowptr) {
    __shared__ int s[256];
    int b = blockIdx.x, t = threadIdx.x;
    int i = b * 256 + t;
    int v = (i < N_NODES) ? deg[i] : 0;
    s[t] = v;
    __syncthreads();
    for (int off = 1; off < 256; off <<= 1) {
        int u = (t >= off) ? s[t - off] : 0;
        __syncthreads();
        s[t] += u;
        __syncthreads();
    }
    if (i < N_NODES) rowptr[i] = boff[b] + s[t] - v;   // exclusive
    if (i == 0) rowptr[N_NODES] = E_EDGES;
}

// binned, atomic-free CSR fill: block handles (chunk, bin); writes only dst in its bin
// -> each bin's 800KB csrsrc region stays L2-resident, lines fill before writeback
__global__ __launch_bounds__(256) void fill_kernel(const int* __restrict__ src,
        const int* __restrict__ dst, const int* __restrict__ slot,
        const int* __restrict__ rowptr, int* __restrict__ csrsrc) {
    int chunk = blockIdx.x >> 3;          // / NBIN
    int bin = blockIdx.x & (NBIN - 1);    // %8 ~ XCD round-robin heuristic
    int lo = bin * BIN_W, hi = lo + BIN_W;
    int base = chunk * FILL_CHUNK + threadIdx.x;
    #pragma unroll
    for (int k = 0; k < FILL_CHUNK / 256; ++k) {
        int i = base + k * 256;
        if (i < E_EDGES) {
            int d = dst[i];
            if (d >= lo && d < hi) csrsrc[rowptr[d] + slot[i]] = src[i];
        }
    }
}

// ------- GEMM (once per call): xw1 = x @ W1, bf16 out -------
__global__ __launch_bounds__(256) void gemm_xw1_kernel(const float* __restrict__ A,
        const float* __restrict__ B, unsigned short* __restrict__ C, int M, int K) {
    __shared__ float As[16][68];
    __shared__ float Bs[16][68];
    int tid = threadIdx.x;
    int tx = tid & 15, ty = tid >> 4;
    int m0 = blockIdx.x * 64, n0 = blockIdx.y * 64;
    int lar = tid >> 2;
    int lac = (tid & 3) << 2;
    int lbr = tid >> 4;
    int lbc = (tid & 15) << 2;
    float acc[4][4] = {};
    for (int kk = 0; kk < K; kk += 16) {
        float4 av = make_float4(0.f, 0.f, 0.f, 0.f);
        if (m0 + lar < M) av = *(const float4*)(A + (size_t)(m0 + lar) * K + kk + lac);
        float4 bv = *(const float4*)(B + (size_t)(kk + lbr) * 256 + n0 + lbc);
        __syncthreads();
        As[lac + 0][lar] = av.x; As[lac + 1][lar] = av.y;
        As[lac + 2][lar] = av.z; As[lac + 3][lar] = av.w;
        *(float4*)(&Bs[lbr][lbc]) = bv;
        __syncthreads();
        #pragma unroll
        for (int k = 0; k < 16; ++k) {
            float4 a4 = *(const float4*)(&As[k][ty << 2]);
            float4 b4 = *(const float4*)(&Bs[k][tx << 2]);
            float a[4] = {a4.x, a4.y, a4.z, a4.w};
            float b[4] = {b4.x, b4.y, b4.z, b4.w};
            #pragma unroll
            for (int i = 0; i < 4; ++i)
                #pragma unroll
                for (int j = 0; j < 4; ++j)
                    acc[i][j] = fmaf(a[i], b[j], acc[i][j]);
        }
    }
    int nb = n0 + (tx << 2);
    #pragma unroll
    for (int i = 0; i < 4; ++i) {
        int m = m0 + (ty << 2) + i;
        if (m < M) {
            ushort4 o;
            o.x = f2bf(acc[i][0]); o.y = f2bf(acc[i][1]);
            o.z = f2bf(acc[i][2]); o.w = f2bf(acc[i][3]);
            *(ushort4*)(C + (size_t)m * 256 + nb) = o;
        }
    }
}

// ------- SpMM layer 0 (fused bias+relu), 4-way edge unroll -------
__global__ __launch_bounds__(256) void spmm_l0_kernel(const unsigned short* __restrict__ xw1,
        const float* __restrict__ dinv, const int* __restrict__ rowptr,
        const int* __restrict__ csrsrc, const float* __restrict__ b1,
        unsigned short* __restrict__ h) {
    int r = (blockIdx.x << 2) + (threadIdx.x >> 6);
    int lane = threadIdx.x & 63;
    int e0 = rowptr[r], e1 = rowptr[r + 1];
    float di = dinv[r];
    float4 acc = make_float4(0.f, 0.f, 0.f, 0.f);
    const ushort4* tp = (const ushort4*)xw1;
    int e = e0;
    for (; e + 4 <= e1; e += 4) {
        int s0 = csrsrc[e], s1 = csrsrc[e + 1], s2 = csrsrc[e + 2], s3 = csrsrc[e + 3];
        float w0 = dinv[s0] * di, w1 = dinv[s1] * di, w2 = dinv[s2] * di, w3 = dinv[s3] * di;
        ushort4 u0 = tp[(size_t)s0 * 64 + lane];
        ushort4 u1 = tp[(size_t)s1 * 64 + lane];
        ushort4 u2 = tp[(size_t)s2 * 64 + lane];
        ushort4 u3 = tp[(size_t)s3 * 64 + lane];
        acc.x = fmaf(bf2f(u0.x), w0, acc.x); acc.y = fmaf(bf2f(u0.y), w0, acc.y);
        acc.z = fmaf(bf2f(u0.z), w0, acc.z); acc.w = fmaf(bf2f(u0.w), w0, acc.w);
        acc.x = fmaf(bf2f(u1.x), w1, acc.x); acc.y = fmaf(bf2f(u1.y), w1, acc.y);
        acc.z = fmaf(bf2f(u1.z), w1, acc.z); acc.w = fmaf(bf2f(u1.w), w1, acc.w);
        acc.x = fmaf(bf2f(u2.x), w2, acc.x); acc.y = fmaf(bf2f(u2.y), w2, acc.y);
        acc.z = fmaf(bf2f(u2.z), w2, acc.z); acc.w = fmaf(bf2f(u2.w), w2, acc.w);
        acc.x = fmaf(bf2f(u3.x), w3, acc.x); acc.y = fmaf(bf2f(u3.y), w3, acc.y);
        acc.z = fmaf(bf2f(u3.z), w3, acc.z); acc.w = fmaf(bf2f(u3.w), w3, acc.w);
    }
    for (; e < e1; ++e) {
        int s = csrsrc[e];
        float wv = dinv[s] * di;
        ushort4 u = tp[(size_t)s * 64 + lane];
        acc.x = fmaf(bf2f(u.x), wv, acc.x); acc.y = fmaf(bf2f(u.y), wv, acc.y);
        acc.z = fmaf(bf2f(u.z), wv, acc.z); acc.w = fmaf(bf2f(u.w), wv, acc.w);
    }
    ushort4 us = tp[(size_t)r * 64 + lane];
    float wd = di * di;
    float4 bb = ((const float4*)b1)[lane];
    ushort4 o;
    o.x = f2bf(fmaxf(fmaf(bf2f(us.x), wd, acc.x) + bb.x, 0.f));
    o.y = f2bf(fmaxf(fmaf(bf2f(us.y), wd, acc.y) + bb.y, 0.f));
    o.z = f2bf(fmaxf(fmaf(bf2f(us.z), wd, acc.z) + bb.z, 0.f));
    o.w = f2bf(fmaxf(fmaf(bf2f(us.w), wd, acc.w) + bb.w, 0.f));
    ((ushort4*)h)[(size_t)r * 64 + lane] = o;
}

// ---------------- SpMM layer 1 (post rows only) ----------------
__global__ __launch_bounds__(256) void spmm_h_post_kernel(const unsigned short* __restrict__ h,
        const float* __restrict__ dinv, const int* __restrict__ rowptr,
        const int* __restrict__ csrsrc, const int* __restrict__ post,
        float* __restrict__ t1p) {
    int p = (blockIdx.x << 2) + (threadIdx.x >> 6);
    int lane = threadIdx.x & 63;
    int r = post[p];
    int e0 = rowptr[r], e1 = rowptr[r + 1];
    float di = dinv[r];
    float4 acc = make_float4(0.f, 0.f, 0.f, 0.f);
    const ushort4* hp = (const ushort4*)h;
    int e = e0;
    for (; e + 4 <= e1; e += 4) {
        int s0 = csrsrc[e], s1 = csrsrc[e + 1], s2 = csrsrc[e + 2], s3 = csrsrc[e + 3];
        float w0 = dinv[s0] * di, w1 = dinv[s1] * di, w2 = dinv[s2] * di, w3 = dinv[s3] * di;
        ushort4 u0 = hp[(size_t)s0 * 64 + lane];
        ushort4 u1 = hp[(size_t)s1 * 64 + lane];
        ushort4 u2 = hp[(size_t)s2 * 64 + lane];
        ushort4 u3 = hp[(size_t)s3 * 64 + lane];
        acc.x = fmaf(bf2f(u0.x), w0, acc.x); acc.y = fmaf(bf2f(u0.y), w0, acc.y);
        acc.z = fmaf(bf2f(u0.z), w0, acc.z); acc.w = fmaf(bf2f(u0.w), w0, acc.w);
        acc.x = fmaf(bf2f(u1.x), w1, acc.x); acc.y = fmaf(bf2f(u1.y), w1, acc.y);
        acc.z = fmaf(bf2f(u1.z), w1, acc.z); acc.w = fmaf(bf2f(u1.w), w1, acc.w);
        acc.x = fmaf(bf2f(u2.x), w2, acc.x); acc.y = fmaf(bf2f(u2.y), w2, acc.y);
        acc.z = fmaf(bf2f(u2.z), w2, acc.z); acc.w = fmaf(bf2f(u2.w), w2, acc.w);
        acc.x = fmaf(bf2f(u3.x), w3, acc.x); acc.y = fmaf(bf2f(u3.y), w3, acc.y);
        acc.z = fmaf(bf2f(u3.z), w3, acc.z); acc.w = fmaf(bf2f(u3.w), w3, acc.w);
    }
    for (; e < e1; ++e) {
        int s = csrsrc[e];
        float wv = dinv[s] * di;
        ushort4 u = hp[(size_t)s * 64 + lane];
        acc.x = fmaf(bf2f(u.x), wv, acc.x); acc.y = fmaf(bf2f(u.y), wv, acc.y);
        acc.z = fmaf(bf2f(u.z), wv, acc.z); acc.w = fmaf(bf2f(u.w), wv, acc.w);
    }
    ushort4 u = hp[(size_t)r * 64 + lane];
    float wd = di * di;
    acc.x = fmaf(bf2f(u.x), wd, acc.x);
    acc.y = fmaf(bf2f(u.y), wd, acc.y);
    acc.z = fmaf(bf2f(u.z), wd, acc.z);
    acc.w = fmaf(bf2f(u.w), wd, acc.w);
    ((float4*)t1p)[(size_t)p * 64 + lane] = acc;
}

// ------- GEMM layer 1 (post rows): accP += t1p @ W2 + b2 + h[post] -------
__global__ __launch_bounds__(256) void gemm_l1_kernel(const float* __restrict__ A,
        const float* __restrict__ B, const float* __restrict__ b2,
        const unsigned short* __restrict__ h, const int* __restrict__ post,
        float* __restrict__ accP, int M) {
    __shared__ float As[16][68];
    __shared__ float Bs[16][68];
    int tid = threadIdx.x;
    int tx = tid & 15, ty = tid >> 4;
    int m0 = blockIdx.x * 64, n0 = blockIdx.y * 64;
    int lar = tid >> 2;
    int lac = (tid & 3) << 2;
    int lbr = tid >> 4;
    int lbc = (tid & 15) << 2;
    float acc[4][4] = {};
    for (int kk = 0; kk < 256; kk += 16) {
        float4 av = make_float4(0.f, 0.f, 0.f, 0.f);
        if (m0 + lar < M) av = *(const float4*)(A + (size_t)(m0 + lar) * 256 + kk + lac);
        float4 bv = *(const float4*)(B + (size_t)(kk + lbr) * 256 + n0 + lbc);
        __syncthreads();
        As[lac + 0][lar] = av.x; As[lac + 1][lar] = av.y;
        As[lac + 2][lar] = av.z; As[lac + 3][lar] = av.w;
        *(float4*)(&Bs[lbr][lbc]) = bv;
        __syncthreads();
        #pragma unroll
        for (int k = 0; k < 16; ++k) {
            float4 a4 = *(const float4*)(&As[k][ty << 2]);
            float4 b4 = *(const float4*)(&Bs[k][tx << 2]);
            float a[4] = {a4.x, a4.y, a4.z, a4.w};
            float b[4] = {b4.x, b4.y, b4.z, b4.w};
            #pragma unroll
            for (int i = 0; i < 4; ++i)
                #pragma unroll
                for (int j = 0; j < 4; ++j)
                    acc[i][j] = fmaf(a[i], b[j], acc[i][j]);
        }
    }
    int nb = n0 + (tx << 2);
    float4 bv = *(const float4*)(b2 + nb);
    float bf[4] = {bv.x, bv.y, bv.z, bv.w};
    #pragma unroll
    for (int i = 0; i < 4; ++i) {
        int m = m0 + (ty << 2) + i;
        if (m < M) {
            int node = post[m];
            ushort4 hr = *(const ushort4*)(h + (size_t)node * 256 + nb);
            float4 a = *(float4*)(accP + (size_t)m * 256 + nb);
            a.x += acc[i][0] + bf[0] + bf2f(hr.x);
            a.y += acc[i][1] + bf[1] + bf2f(hr.y);
            a.z += acc[i][2] + bf[2] + bf2f(hr.z);
            a.w += acc[i][3] + bf[3] + bf2f(hr.w);
            *(float4*)(accP + (size_t)m * 256 + nb) = a;
        }
    }
}

// ---------------- classifier ----------------
__global__ __launch_bounds__(128) void classifier_kernel(const float* __restrict__ accP,
        const float* __restrict__ Wc1, const float* __restrict__ bc1,
        const float* __restrict__ Wc2, const float* __restrict__ bc2,
        float* __restrict__ out) {
    __shared__ float arow[8][256];
    __shared__ float red[2][8];
    int p0 = blockIdx.x << 3;
    int tid = threadIdx.x;
    for (int idx = tid; idx < 8 * 256; idx += 128) {
        int pl = idx >> 8, k = idx & 255;
        arow[pl][k] = 0.25f * accP[(size_t)(p0 + pl) * 256 + k];
    }
    __syncthreads();
    float s[8];
    float b = bc1[tid];
    #pragma unroll
    for (int pl = 0; pl < 8; ++pl) s[pl] = b;
    for (int k = 0; k < 256; ++k) {
        float wv = Wc1[k * 128 + tid];
        #pragma unroll
        for (int pl = 0; pl < 8; ++pl) s[pl] = fmaf(arow[pl][k], wv, s[pl]);
    }
    float wc2 = Wc2[tid];
    float part[8];
    #pragma unroll
    for (int pl = 0; pl < 8; ++pl) part[pl] = fmaxf(s[pl], 0.f) * wc2;
    #pragma unroll
    for (int off = 32; off > 0; off >>= 1)
        #pragma unroll
        for (int pl = 0; pl < 8; ++pl) part[pl] += __shfl_down(part[pl], off, 64);
    int wave = tid >> 6, lane = tid & 63;
    if (lane == 0) {
        #pragma unroll
        for (int pl = 0; pl < 8; ++pl) red[wave][pl] = part[pl];
    }
    __syncthreads();
    if (tid < 8) {
        float logit = red[0][tid] + red[1][tid] + bc2[0];
        out[p0 + tid] = 1.f / (1.f + expf(-logit));
    }
}

extern "C" void kernel_launch(void* const* d_in, const int* in_sizes, int n_in,
                              void* d_out, int out_size, void* d_ws, size_t ws_size,
                              hipStream_t stream) {
    const float* x   = (const float*)d_in[0];
    const int*   ei  = (const int*)d_in[1];
    const int*   post= (const int*)d_in[2];
    const float* W1  = (const float*)d_in[3];
    const float* b1  = (const float*)d_in[4];
    const float* W2  = (const float*)d_in[5];
    const float* b2  = (const float*)d_in[6];
    const float* Wc1 = (const float*)d_in[7];
    const float* bc1 = (const float*)d_in[8];
    const float* Wc2 = (const float*)d_in[9];
    const float* bc2 = (const float*)d_in[10];
    float* out = (float*)d_out;

    char* w = (char*)d_ws;
    size_t off = 0;
#define WS_ALLOC(type, name, count) \
    type* name = (type*)(w + off); \
    off += (((size_t)(count) * sizeof(type)) + 255) & ~(size_t)255;
    WS_ALLOC(unsigned short, xw1,  (size_t)N_NODES * H_DIM)   // 51.2 MB (bf16)
    WS_ALLOC(unsigned short, hbuf, (size_t)N_NODES * H_DIM)   // 51.2 MB (bf16)
    WS_ALLOC(float,          t1p,  (size_t)P_POST * H_DIM)    // 10.24 MB (aliased by slot)
    WS_ALLOC(float,          accP, (size_t)P_POST * H_DIM)    // 10.24 MB
    WS_ALLOC(int,            deg,    N_NODES)
    WS_ALLOC(float,          dinvb,  N_NODES)
    WS_ALLOC(int,            rowptr, N_NODES + 1)
    WS_ALLOC(int,            csrsrc, E_EDGES)                 // 6.4 MB -> total ~131 MB
    WS_ALLOC(int,            bsum,   SCAN_NBLK)
    WS_ALLOC(int,            boff,   SCAN_NBLK)
#undef WS_ALLOC
    // slot[i] (6.4 MB) aliases t1p's region: dead by the time spmm_h_post writes t1p
    int* slot = (int*)t1p;
    (void)ws_size; (void)in_sizes; (void)n_in; (void)out_size;

    zero32_kernel<<<(P_POST * H_DIM + 255) / 256, 256, 0, stream>>>((unsigned int*)accP, P_POST * H_DIM);

    // xw1 = x @ W1 once per call (snapshot-invariant)
    dim3 gg((N_NODES + 63) / 64, 4);
    gemm_xw1_kernel<<<gg, 256, 0, stream>>>(x, W1, xw1, N_NODES, D_IN);

    for (int s = 0; s < S_SNAP; ++s) {
        const int* srcs = ei + (size_t)s * 2 * E_EDGES;
        const int* dsts = srcs + E_EDGES;
        zero32_kernel<<<(N_NODES + 255) / 256, 256, 0, stream>>>((unsigned int*)deg, N_NODES);
        hist_kernel<<<E_EDGES / 256, 256, 0, stream>>>(dsts, deg, slot);
        dinv_kernel<<<(N_NODES + 255) / 256, 256, 0, stream>>>(deg, dinvb);
        scan_part_kernel<<<SCAN_NBLK, 256, 0, stream>>>(deg, bsum);
        scan_top_kernel<<<1, 512, 0, stream>>>(bsum, boff);
        scan_fin_kernel<<<SCAN_NBLK, 256, 0, stream>>>(deg, boff, rowptr);
        // atomic-free binned CSR fill
        fill_kernel<<<FILL_NCHUNK * NBIN, 256, 0, stream>>>(srcs, dsts, slot, rowptr, csrsrc);
        // h = relu(Ahat @ xw1 + b1)   [N,256] bf16  (fused epilogue)
        spmm_l0_kernel<<<N_NODES / 4, 256, 0, stream>>>(xw1, dinvb, rowptr, csrsrc, b1, hbuf);
        // t1p = (Ahat @ h)[post]   [P,256] fp32   (overwrites slot region — slot is dead)
        spmm_h_post_kernel<<<P_POST / 4, 256, 0, stream>>>(hbuf, dinvb, rowptr, csrsrc, post, t1p);
        // accP += t1p @ W2 + b2 + h[post]
        dim3 g1((P_POST + 63) / 64, 4);
        gemm_l1_kernel<<<g1, 256, 0, stream>>>(t1p, W2, b2, hbuf, post, accP, P_POST);
    }
    classifier_kernel<<<P_POST / 8, 128, 0, stream>>>(accP, Wc1, bc1, Wc2, bc2, out);
}